// Round 2
// baseline (455.551 us; speedup 1.0000x reference)
//
#include <hip/hip_runtime.h>
#include <hip/hip_bf16.h>

#define DEV_INLINE __device__ __forceinline__

typedef __bf16 bf16x8 __attribute__((ext_vector_type(8)));
typedef float  floatx4 __attribute__((ext_vector_type(4)));

DEV_INLINE bf16x8 ld_frag(const __bf16* p) {
    union { uint4 u; bf16x8 v; } t;
    t.u = *(const uint4*)p;
    return t.v;
}
// relu + pack two f32x4 accumulators into the next layer's B-fragment.
// Element j of the frag = relu(acc[2kq + (j>>2)][j&3]) -> matches tp_perm:
// feat(k_hw) = (2*kq + (j>>2))*16 + qd*4 + (j&3).
DEV_INLINE bf16x8 pack_relu2(floatx4 a, floatx4 b) {
    float2 p0 = {fmaxf(a[0], 0.0f), fmaxf(a[1], 0.0f)};
    float2 p1 = {fmaxf(a[2], 0.0f), fmaxf(a[3], 0.0f)};
    float2 p2 = {fmaxf(b[0], 0.0f), fmaxf(b[1], 0.0f)};
    float2 p3 = {fmaxf(b[2], 0.0f), fmaxf(b[3], 0.0f)};
    union { __hip_bfloat162 h[4]; bf16x8 v; } t;
    t.h[0] = __float22bfloat162_rn(p0);
    t.h[1] = __float22bfloat162_rn(p1);
    t.h[2] = __float22bfloat162_rn(p2);
    t.h[3] = __float22bfloat162_rn(p3);
    return t.v;
}
DEV_INLINE floatx4 vmax4(floatx4 a, floatx4 b) {
    floatx4 r;
#pragma unroll
    for (int i = 0; i < 4; ++i) r[i] = fmaxf(a[i], b[i]);
    return r;
}

// ---------------------------------------------------------------------------
// Prep. tp: natural transpose+pad (A-layout [n][k]). tp_perm: k-permuted so
// the consumer uses the previous layer's accumulators directly as B operand.
// ---------------------------------------------------------------------------
template<int N, int Kp, int Ks>
DEV_INLINE void tp(__bf16* dst, const float* __restrict__ src, int idx0, int stride) {
    for (int e = idx0; e < N * Kp; e += stride) {
        int n = e / Kp, k = e - n * Kp;
        dst[e] = (k < Ks) ? (__bf16)src[k * N + n] : (__bf16)0.0f;
    }
}
template<int N, int K>   // dst[n][k_hw] = src[c(k_hw)][n]
DEV_INLINE void tp_perm(__bf16* dst, const float* __restrict__ src, int idx0, int stride) {
    for (int e = idx0; e < N * K; e += stride) {
        int n = e / K, kh = e - n * K;
        int qd = (kh >> 3) & 3, kq = kh >> 5, j = kh & 7;
        int c = (2 * kq + (j >> 2)) * 16 + qd * 4 + (j & 3);
        dst[e] = (__bf16)src[c * N + n];
    }
}

__global__ __launch_bounds__(256)
void prep_kernel(const float* __restrict__ rw1, const float* __restrict__ rw2,
                 const float* __restrict__ rw3,
                 const float* __restrict__ tw1, const float* __restrict__ tw2,
                 const float* __restrict__ tw3,
                 const float* __restrict__ mw1, const float* __restrict__ mw2,
                 const float* __restrict__ mw3, __bf16* __restrict__ wb)
{
    int i0 = blockIdx.x * 256 + threadIdx.x;
    int st = gridDim.x * 256;
    tp     < 64,  32,   6>(wb + 0,     rw1, i0, st);
    tp_perm< 64,  64>     (wb + 2048,  rw2, i0, st);
    tp_perm< 32,  64>     (wb + 6144,  rw3, i0, st);
    tp     < 64,  32,   7>(wb + 8192,  tw1, i0, st);
    tp_perm< 64,  64>     (wb + 10240, tw2, i0, st);
    tp_perm< 32,  64>     (wb + 14336, tw3, i0, st);
    tp     <128, 128, 108>(wb + 16384, mw1, i0, st);
    tp_perm<128, 128>     (wb + 32768, mw2, i0, st);
    tp_perm< 64, 128>     (wb + 49152, mw3, i0, st);
}

// ---------------------------------------------------------------------------
// Persistent fused encoder, R9: R8 + (a) e3 stride 37 float2 (conflict-free
// 16-lane float4 stores: bank base 10*ln mod 32, all distinct), (b) biases
// register-resident, fed directly as MFMA C operand (no per-iter ds_read /
// v_mov init), (c) hoisted zero x-frag.
// ---------------------------------------------------------------------------
struct __align__(16) EncSmem {
    float2 e3[64 * 37];      // (sum,max) per part-row  18944 B
    float2 pool[256];        //                          2048 B
    __bf16 xs[2][128 * 8];   // x tiles, k padded to 8   4096 B
};

template<int DIN>
DEV_INLINE void x_load(const float* __restrict__ X, int bid, int tid, float (&g)[4]) {
    const float* src = X + (size_t)bid * 128 * DIN;
#pragma unroll
    for (int p = 0; p < 4; ++p) {
        int e = tid + p * 256;
        if ((DIN == 6) ? (p < 3) : (e < 128 * 7)) g[p] = src[e];
    }
}
template<int DIN>
DEV_INLINE void x_store(__bf16* xbuf, int tid, const float (&g)[4]) {
#pragma unroll
    for (int p = 0; p < 4; ++p) {
        int e = tid + p * 256;
        if ((DIN == 6) ? (p < 3) : (e < 128 * 7)) {
            int r = e / DIN, k = e - r * DIN;
            xbuf[r * 8 + k] = (__bf16)g[p];
        }
    }
}

template<int DIN, int S, int ITERS>
DEV_INLINE void enc_loop(EncSmem& sm, const float* __restrict__ X,
                         const __bf16* __restrict__ w1p,
                         const __bf16* __restrict__ w2p,
                         const __bf16* __restrict__ w3p,
                         const float* __restrict__ b1, const float* __restrict__ b2,
                         const float* __restrict__ b3,
                         __bf16* __restrict__ out, int bid0)
{
    constexpr int NB = 128 / S;
    const int tid = threadIdx.x;
    const int w   = tid >> 6;
    const int l64 = tid & 63;
    const int ln  = l64 & 15;
    const int qd  = l64 >> 4;

    // zero the k in [DIN,8) pad of both x buffers once (x_store never touches it)
    {
        __bf16* xf = &sm.xs[0][0];
        if (DIN == 6) *(uint32_t*)&xf[tid * 8 + 6] = 0u;   // rows 0..255 across both bufs
        else          xf[tid * 8 + 7] = (__bf16)0.0f;
    }

    // ---- weights + biases -> registers, once per block ----
    bf16x8 w1f[4], w2f[4][2], w3f[2][2];
    floatx4 bv1[4], bv2[4], bv3[2];
#pragma unroll
    for (int mt = 0; mt < 4; ++mt) {
        w1f[mt] = ld_frag(&w1p[(mt * 16 + ln) * 32 + qd * 8]);
        bv1[mt] = *(const floatx4*)&b1[mt * 16 + qd * 4];
        bv2[mt] = *(const floatx4*)&b2[mt * 16 + qd * 4];
    }
#pragma unroll
    for (int mt = 0; mt < 4; ++mt)
#pragma unroll
        for (int kq = 0; kq < 2; ++kq)
            w2f[mt][kq] = ld_frag(&w2p[(mt * 16 + ln) * 64 + kq * 32 + qd * 8]);
#pragma unroll
    for (int mt = 0; mt < 2; ++mt) {
        bv3[mt] = *(const floatx4*)&b3[mt * 16 + qd * 4];
#pragma unroll
        for (int kq = 0; kq < 2; ++kq)
            w3f[mt][kq] = ld_frag(&w3p[(mt * 16 + ln) * 64 + kq * 32 + qd * 8]);
    }

    // hoisted zero B-frag for qd!=0 lanes
    bf16x8 zf;
#pragma unroll
    for (int j = 0; j < 8; ++j) zf[j] = (__bf16)0.0f;

    // ---- prologue: stage x for iter 0 ----
    float g[4];
    x_load<DIN>(X, bid0, tid, g);
    x_store<DIN>(sm.xs[0], tid, g);
    __syncthreads();

    int cur = 0;
    for (int it = 0; it < ITERS; ++it) {
        const int bid = bid0 + it;
        // issue next tile's global loads early; consumed after sync1 (latency
        // hidden under the whole L1->L3 compute)
        if (it + 1 < ITERS) x_load<DIN>(X, bid + 1, tid, g);

        // ---- build x B-frags from LDS (2-way-conflict-free ds_read_b128) ----
        bf16x8 xb[2];
#pragma unroll
        for (int t = 0; t < 2; ++t) {
            bf16x8 v = zf;
            if (qd == 0) {
                const int row = (2 * w + t) * 16 + ln;
                v = ld_frag(&sm.xs[cur][row * 8]);
            }
            xb[t] = v;
        }

        // ---- L1: K=32 (weights zero-padded); bias regs direct as C ----
        floatx4 a1[2][4];
#pragma unroll
        for (int mt = 0; mt < 4; ++mt)
#pragma unroll
            for (int t = 0; t < 2; ++t)
                a1[t][mt] = __builtin_amdgcn_mfma_f32_16x16x32_bf16(w1f[mt], xb[t], bv1[mt], 0, 0, 0);
        bf16x8 f1[2][2];
#pragma unroll
        for (int t = 0; t < 2; ++t)
#pragma unroll
            for (int kq = 0; kq < 2; ++kq)
                f1[t][kq] = pack_relu2(a1[t][2 * kq], a1[t][2 * kq + 1]);

        // ---- L2: 64 -> 64 ----
        floatx4 a2[2][4];
#pragma unroll
        for (int mt = 0; mt < 4; ++mt)
#pragma unroll
            for (int t = 0; t < 2; ++t) {
                floatx4 acc;
                acc = __builtin_amdgcn_mfma_f32_16x16x32_bf16(w2f[mt][0], f1[t][0], bv2[mt], 0, 0, 0);
                acc = __builtin_amdgcn_mfma_f32_16x16x32_bf16(w2f[mt][1], f1[t][1], acc, 0, 0, 0);
                a2[t][mt] = acc;
            }
        bf16x8 f2[2][2];
#pragma unroll
        for (int t = 0; t < 2; ++t)
#pragma unroll
            for (int kq = 0; kq < 2; ++kq)
                f2[t][kq] = pack_relu2(a2[t][2 * kq], a2[t][2 * kq + 1]);

        // ---- L3: 64 -> 32 (fp32, in regs) ----
        floatx4 a3[2][2];
#pragma unroll
        for (int mt = 0; mt < 2; ++mt)
#pragma unroll
            for (int t = 0; t < 2; ++t) {
                floatx4 acc;
                acc = __builtin_amdgcn_mfma_f32_16x16x32_bf16(w3f[mt][0], f2[t][0], bv3[mt], 0, 0, 0);
                acc = __builtin_amdgcn_mfma_f32_16x16x32_bf16(w3f[mt][1], f2[t][1], acc, 0, 0, 0);
                a3[t][mt] = acc;
            }
        // ---- in-register t-combine, store interleaved (sum,max) partials ----
#pragma unroll
        for (int mt = 0; mt < 2; ++mt) {
            floatx4 s = a3[0][mt] + a3[1][mt];
            floatx4 m = vmax4(a3[0][mt], a3[1][mt]);
            float4 lo = {s[0], m[0], s[1], m[1]};
            float4 hi = {s[2], m[2], s[3], m[3]};
            float2* dst = &sm.e3[(w * 16 + ln) * 37 + mt * 16 + qd * 4];
            *(float4*)&dst[0] = lo;
            *(float4*)&dst[2] = hi;
        }
        __syncthreads();

        // ---- pool phase 1 (all threads) + stage next x into the other buffer
        {
            constexpr int R = 64 / NB;
            const int o  = tid & 31;
            const int bi = (tid >> 5) % NB;
            const int ch = tid / (32 * NB);
            const int p0 = bi * R + ch * 8;
            float s = 0.0f, m = -3.4e38f;
#pragma unroll
            for (int r = 0; r < 8; ++r) {
                float2 v = sm.e3[(p0 + r) * 37 + o];
                s += v.x;
                m = fmaxf(m, v.y);
            }
            sm.pool[tid] = make_float2(s, m);
        }
        if (it + 1 < ITERS) x_store<DIN>(sm.xs[cur ^ 1], tid, g);
        __syncthreads();

        // ---- pool phase 2 ----
        if (tid < NB * 32) {
            constexpr int C = 8 / NB;
            float s = 0.0f, m = -3.4e38f;
#pragma unroll
            for (int c = 0; c < C; ++c) {
                float2 v = sm.pool[tid + c * 32 * NB];
                s += v.x;
                m = fmaxf(m, v.y);
            }
            size_t b = (size_t)bid * NB + (tid >> 5);
            out[b * 32 + (tid & 31)] = (__bf16)(0.5f * (s * (1.0f / S) + m));
        }
        cur ^= 1;
    }
}

__global__ __launch_bounds__(256, 4)
void enc_fused(const float* __restrict__ rX, const float* __restrict__ tX,
               const __bf16* __restrict__ wb,
               const float* __restrict__ rb1, const float* __restrict__ rb2,
               const float* __restrict__ rb3,
               const float* __restrict__ tb1, const float* __restrict__ tb2,
               const float* __restrict__ tb3,
               __bf16* __restrict__ remb, __bf16* __restrict__ temb)
{
    __shared__ EncSmem sm;
    if ((int)blockIdx.x < 1024)
        enc_loop<6, 64, 8>(sm, rX, wb, wb + 2048, wb + 6144,
                           rb1, rb2, rb3, remb, blockIdx.x * 8);
    else
        enc_loop<7, 128, 8>(sm, tX, wb + 8192, wb + 10240, wb + 14336,
                            tb1, tb2, tb3, temb, ((int)blockIdx.x - 1024) * 8);
}

// ---------------------------------------------------------------------------
// Head, register-chained (R7): stage c (1 barrier), then L1->L2->L3->dot in
// regs per wave (16 rows each). hw2/hw3 k-permuted; hw1/b*/w4 natural.
// ---------------------------------------------------------------------------
__global__ __launch_bounds__(256)
void head_mfma(const float* __restrict__ t0,
               const __bf16* __restrict__ remb, const __bf16* __restrict__ temb,
               const __bf16* __restrict__ hw1, const float* __restrict__ b1,
               const __bf16* __restrict__ hw2, const float* __restrict__ b2,
               const __bf16* __restrict__ hw3, const float* __restrict__ b3,
               const float* __restrict__ w4, const float* __restrict__ b4,
               float* __restrict__ out)
{
    __shared__ __align__(16) __bf16 cb[64 * 136];

    const int tid = threadIdx.x;
    const int w   = tid >> 6;
    const int l64 = tid & 63;
    const int ln  = l64 & 15;
    const int qd  = l64 >> 4;
    const int g0  = blockIdx.x * 64;

    for (int i = tid; i < 64 * 44; i += 256) {
        int r = i / 44, k = i - r * 44;
        cb[r * 136 + k] = (__bf16)t0[(size_t)(g0 + r) * 44 + k];
    }
    for (int i = tid; i < 64 * 32; i += 256) {
        int r = i >> 5, k = i & 31;
        cb[r * 136 + 44 + k] = remb[(size_t)(g0 + r) * 32 + k];
        cb[r * 136 + 76 + k] = temb[(size_t)(g0 + r) * 32 + k];
    }
    for (int i = tid; i < 64 * 20; i += 256) {
        int r = i / 20, k = i - r * 20;
        cb[r * 136 + 108 + k] = (__bf16)0.0f;
    }
    __syncthreads();

    bf16x8 cf[4];
#pragma unroll
    for (int kq = 0; kq < 4; ++kq)
        cf[kq] = ld_frag(&cb[(w * 16 + ln) * 136 + kq * 32 + qd * 8]);
    floatx4 acc1[8];
#pragma unroll
    for (int mt = 0; mt < 8; ++mt) {
        float4 bv = *(const float4*)&b1[mt * 16 + qd * 4];
        floatx4 acc = (floatx4){bv.x, bv.y, bv.z, bv.w};
#pragma unroll
        for (int kq = 0; kq < 4; ++kq) {
            bf16x8 af = ld_frag(&hw1[(mt * 16 + ln) * 128 + kq * 32 + qd * 8]);
            acc = __builtin_amdgcn_mfma_f32_16x16x32_bf16(af, cf[kq], acc, 0, 0, 0);
        }
        acc1[mt] = acc;
    }
    bf16x8 f1[4];
#pragma unroll
    for (int kq = 0; kq < 4; ++kq)
        f1[kq] = pack_relu2(acc1[2 * kq], acc1[2 * kq + 1]);

    floatx4 acc2[8];
#pragma unroll
    for (int mt = 0; mt < 8; ++mt) {
        float4 bv = *(const float4*)&b2[mt * 16 + qd * 4];
        floatx4 acc = (floatx4){bv.x, bv.y, bv.z, bv.w};
#pragma unroll
        for (int kq = 0; kq < 4; ++kq) {
            bf16x8 af = ld_frag(&hw2[(mt * 16 + ln) * 128 + kq * 32 + qd * 8]);
            acc = __builtin_amdgcn_mfma_f32_16x16x32_bf16(af, f1[kq], acc, 0, 0, 0);
        }
        acc2[mt] = acc;
    }
    bf16x8 f2[4];
#pragma unroll
    for (int kq = 0; kq < 4; ++kq)
        f2[kq] = pack_relu2(acc2[2 * kq], acc2[2 * kq + 1]);

    floatx4 acc3[4];
#pragma unroll
    for (int mt = 0; mt < 4; ++mt) {
        float4 bv = *(const float4*)&b3[mt * 16 + qd * 4];
        floatx4 acc = (floatx4){bv.x, bv.y, bv.z, bv.w};
#pragma unroll
        for (int kq = 0; kq < 4; ++kq) {
            bf16x8 af = ld_frag(&hw3[(mt * 16 + ln) * 128 + kq * 32 + qd * 8]);
            acc = __builtin_amdgcn_mfma_f32_16x16x32_bf16(af, f2[kq], acc, 0, 0, 0);
        }
        acc3[mt] = acc;
    }

    float part = 0.0f;
#pragma unroll
    for (int mt = 0; mt < 4; ++mt) {
        float4 wv = *(const float4*)&w4[mt * 16 + qd * 4];
        part = fmaf(fmaxf(acc3[mt][0], 0.0f), wv.x, part);
        part = fmaf(fmaxf(acc3[mt][1], 0.0f), wv.y, part);
        part = fmaf(fmaxf(acc3[mt][2], 0.0f), wv.z, part);
        part = fmaf(fmaxf(acc3[mt][3], 0.0f), wv.w, part);
    }
    part += __shfl_xor(part, 16);
    part += __shfl_xor(part, 32);
    if (qd == 0)
        out[g0 + w * 16 + ln] = part + b4[0];
}

extern "C" void kernel_launch(void* const* d_in, const int* in_sizes, int n_in,
                              void* d_out, int out_size, void* d_ws, size_t ws_size,
                              hipStream_t stream)
{
    const float* t0  = (const float*)d_in[0];
    const float* rX  = (const float*)d_in[1];
    const float* tX  = (const float*)d_in[2];
    const float* rw1 = (const float*)d_in[3];  const float* rb1 = (const float*)d_in[4];
    const float* rw2 = (const float*)d_in[5];  const float* rb2 = (const float*)d_in[6];
    const float* rw3 = (const float*)d_in[7];  const float* rb3 = (const float*)d_in[8];
    const float* tw1 = (const float*)d_in[9];  const float* tb1 = (const float*)d_in[10];
    const float* tw2 = (const float*)d_in[11]; const float* tb2 = (const float*)d_in[12];
    const float* tw3 = (const float*)d_in[13]; const float* tb3 = (const float*)d_in[14];
    const float* mw1 = (const float*)d_in[15]; const float* mb1 = (const float*)d_in[16];
    const float* mw2 = (const float*)d_in[17]; const float* mb2 = (const float*)d_in[18];
    const float* mw3 = (const float*)d_in[19]; const float* mb3 = (const float*)d_in[20];
    const float* mw4 = (const float*)d_in[21]; const float* mb4 = (const float*)d_in[22];
    float* out = (float*)d_out;

    const int B = 16384;
    __bf16* remb = (__bf16*)d_ws;
    __bf16* temb = (__bf16*)((char*)d_ws + ((size_t)1 << 20));
    __bf16* wb   = (__bf16*)((char*)d_ws + ((size_t)2 << 20));
    const __bf16* mw1b = wb + 16384; const __bf16* mw2b = wb + 32768;
    const __bf16* mw3b = wb + 49152;

    prep_kernel<<<64, 256, 0, stream>>>(rw1, rw2, rw3, tw1, tw2, tw3,
                                        mw1, mw2, mw3, wb);
    enc_fused<<<3072, 256, 0, stream>>>(rX, tX, wb,
                                        rb1, rb2, rb3, tb1, tb2, tb3,
                                        remb, temb);
    head_mfma<<<B / 64, 256, 0, stream>>>(t0, remb, temb,
                                          mw1b, mb1, mw2b, mb2, mw3b, mb3,
                                          mw4, mb4, out);
}

// Round 3
// 226.289 us; speedup vs baseline: 2.0131x; 2.0131x over previous
//
#include <hip/hip_runtime.h>
#include <hip/hip_bf16.h>

#define DEV_INLINE __device__ __forceinline__

typedef __bf16 bf16x8 __attribute__((ext_vector_type(8)));
typedef float  floatx4 __attribute__((ext_vector_type(4)));

DEV_INLINE bf16x8 ld_frag(const __bf16* p) {
    union { uint4 u; bf16x8 v; } t;
    t.u = *(const uint4*)p;
    return t.v;
}
// relu + pack two f32x4 accumulators into the next layer's B-fragment.
// Element j of the frag = relu(acc[2kq + (j>>2)][j&3]) -> matches tp_perm:
// feat(k_hw) = (2*kq + (j>>2))*16 + qd*4 + (j&3).
DEV_INLINE bf16x8 pack_relu2(floatx4 a, floatx4 b) {
    float2 p0 = {fmaxf(a[0], 0.0f), fmaxf(a[1], 0.0f)};
    float2 p1 = {fmaxf(a[2], 0.0f), fmaxf(a[3], 0.0f)};
    float2 p2 = {fmaxf(b[0], 0.0f), fmaxf(b[1], 0.0f)};
    float2 p3 = {fmaxf(b[2], 0.0f), fmaxf(b[3], 0.0f)};
    union { __hip_bfloat162 h[4]; bf16x8 v; } t;
    t.h[0] = __float22bfloat162_rn(p0);
    t.h[1] = __float22bfloat162_rn(p1);
    t.h[2] = __float22bfloat162_rn(p2);
    t.h[3] = __float22bfloat162_rn(p3);
    return t.v;
}
DEV_INLINE floatx4 vmax4(floatx4 a, floatx4 b) {
    floatx4 r;
#pragma unroll
    for (int i = 0; i < 4; ++i) r[i] = fmaxf(a[i], b[i]);
    return r;
}

// ---------------------------------------------------------------------------
// Prep. tp: natural transpose+pad (A-layout [n][k]). tp_b: same, with the
// bias placed in padded row k==Ks (consumer sets x[k=Ks]=1.0). tp_perm:
// k-permuted so the consumer uses the previous layer's accumulators directly.
// ---------------------------------------------------------------------------
template<int N, int Kp, int Ks>
DEV_INLINE void tp(__bf16* dst, const float* __restrict__ src, int idx0, int stride) {
    for (int e = idx0; e < N * Kp; e += stride) {
        int n = e / Kp, k = e - n * Kp;
        dst[e] = (k < Ks) ? (__bf16)src[k * N + n] : (__bf16)0.0f;
    }
}
template<int N, int Kp, int Ks>
DEV_INLINE void tp_b(__bf16* dst, const float* __restrict__ src,
                     const float* __restrict__ bias, int idx0, int stride) {
    for (int e = idx0; e < N * Kp; e += stride) {
        int n = e / Kp, k = e - n * Kp;
        float v = (k < Ks) ? src[k * N + n] : ((k == Ks) ? bias[n] : 0.0f);
        dst[e] = (__bf16)v;
    }
}
template<int N, int K>   // dst[n][k_hw] = src[c(k_hw)][n]
DEV_INLINE void tp_perm(__bf16* dst, const float* __restrict__ src, int idx0, int stride) {
    for (int e = idx0; e < N * K; e += stride) {
        int n = e / K, kh = e - n * K;
        int qd = (kh >> 3) & 3, kq = kh >> 5, j = kh & 7;
        int c = (2 * kq + (j >> 2)) * 16 + qd * 4 + (j & 3);
        dst[e] = (__bf16)src[c * N + n];
    }
}

__global__ __launch_bounds__(256)
void prep_kernel(const float* __restrict__ rw1, const float* __restrict__ rb1,
                 const float* __restrict__ rw2, const float* __restrict__ rw3,
                 const float* __restrict__ tw1, const float* __restrict__ tb1,
                 const float* __restrict__ tw2, const float* __restrict__ tw3,
                 const float* __restrict__ mw1, const float* __restrict__ mw2,
                 const float* __restrict__ mw3, __bf16* __restrict__ wb)
{
    int i0 = blockIdx.x * 256 + threadIdx.x;
    int st = gridDim.x * 256;
    tp_b   < 64,  32,   6>(wb + 0,     rw1, rb1, i0, st);
    tp_perm< 64,  64>     (wb + 2048,  rw2, i0, st);
    tp_perm< 32,  64>     (wb + 6144,  rw3, i0, st);
    tp_b   < 64,  32,   7>(wb + 8192,  tw1, tb1, i0, st);
    tp_perm< 64,  64>     (wb + 10240, tw2, i0, st);
    tp_perm< 32,  64>     (wb + 14336, tw3, i0, st);
    tp     <128, 128, 108>(wb + 16384, mw1, i0, st);
    tp_perm<128, 128>     (wb + 32768, mw2, i0, st);
    tp_perm< 64, 128>     (wb + 49152, mw3, i0, st);
}

// ---------------------------------------------------------------------------
// Persistent fused encoder, R10: flipped L3 (A=f2, B=w3) puts set-rows in the
// accumulator ROW dim -> pooling is in-register (+2 shfl levels), e3 LDS and
// one barrier per iter eliminated. b1 folded into weight pad row (x pad=1.0),
// b3 folded past pooling (constant across set rows). LDS 6.4 KB.
// ---------------------------------------------------------------------------
struct __align__(16) EncSmem {
    float2 pb[2 * 4 * 32];   // wave partials (sum,max), dbuf  2048 B
    float  bs[64];           // b2                              256 B
    __bf16 xs[2][128 * 8];   // x tiles, k padded to 8         4096 B
};

template<int DIN>
DEV_INLINE void x_load(const float* __restrict__ X, int bid, int tid, float (&g)[4]) {
    const float* src = X + (size_t)bid * 128 * DIN;
#pragma unroll
    for (int p = 0; p < 4; ++p) {
        int e = tid + p * 256;
        if ((DIN == 6) ? (p < 3) : (e < 128 * 7)) g[p] = src[e];
    }
}
template<int DIN>
DEV_INLINE void x_store(__bf16* xbuf, int tid, const float (&g)[4]) {
#pragma unroll
    for (int p = 0; p < 4; ++p) {
        int e = tid + p * 256;
        if ((DIN == 6) ? (p < 3) : (e < 128 * 7)) {
            int r = e / DIN, k = e - r * DIN;
            xbuf[r * 8 + k] = (__bf16)g[p];
        }
    }
}

template<int DIN, int S, int ITERS>
DEV_INLINE void enc_loop(EncSmem& sm, const float* __restrict__ X,
                         const __bf16* __restrict__ w1p,
                         const __bf16* __restrict__ w2p,
                         const __bf16* __restrict__ w3p,
                         const float* __restrict__ b2, const float* __restrict__ b3,
                         __bf16* __restrict__ out, int bid0)
{
    constexpr int NB = 128 / S;          // batches per 128-row tile
    const int tid = threadIdx.x;
    const int w   = tid >> 6;
    const int l64 = tid & 63;
    const int ln  = l64 & 15;
    const int qd  = l64 >> 4;

    if (tid < 64) sm.bs[tid] = b2[tid];

    // pad init: k in [DIN,8) of both x buffers; bias slot k==DIN gets 1.0
    {
        __bf16* xf = &sm.xs[0][0];
        if (DIN == 6) {
            union { __bf16 h[2]; uint32_t u; } c;
            c.h[0] = (__bf16)1.0f; c.h[1] = (__bf16)0.0f;
            *(uint32_t*)&xf[tid * 8 + 6] = c.u;   // rows 0..255 across both bufs
        } else {
            xf[tid * 8 + 7] = (__bf16)1.0f;
        }
    }
    // b3 folded past pooling: e-row = Wx + b3 -> 0.5*(mean+max) = 0.5*(s/S+m)+b3[f]
    const float b3f = (tid < NB * 32) ? b3[tid & 31] : 0.0f;

    // ---- weights -> registers, once per block (global, L2-resident) ----
    bf16x8 w1f[4], w2f[4][2], w3f[2][2];
#pragma unroll
    for (int mt = 0; mt < 4; ++mt)
        w1f[mt] = ld_frag(&w1p[(mt * 16 + ln) * 32 + qd * 8]);
#pragma unroll
    for (int mt = 0; mt < 4; ++mt)
#pragma unroll
        for (int kq = 0; kq < 2; ++kq)
            w2f[mt][kq] = ld_frag(&w2p[(mt * 16 + ln) * 64 + kq * 32 + qd * 8]);
#pragma unroll
    for (int mt = 0; mt < 2; ++mt)
#pragma unroll
        for (int kq = 0; kq < 2; ++kq)
            w3f[mt][kq] = ld_frag(&w3p[(mt * 16 + ln) * 64 + kq * 32 + qd * 8]);

    bf16x8 zf;
#pragma unroll
    for (int j = 0; j < 8; ++j) zf[j] = (__bf16)0.0f;
    const floatx4 z4 = {0.0f, 0.0f, 0.0f, 0.0f};

    // ---- prologue: stage x for iter 0 ----
    float g[4];
    x_load<DIN>(X, bid0, tid, g);
    x_store<DIN>(sm.xs[0], tid, g);
    __syncthreads();

    int cur = 0, pbuf = 0;
    for (int it = 0; it < ITERS; ++it) {
        const int bid = bid0 + it;
        // issue next tile's global loads early; stored late (latency hidden
        // under the whole L1->L3 compute). Writing xs[cur^1] needs no barrier:
        // its last reads were ordered by the previous iter's barrier.
        if (it + 1 < ITERS) x_load<DIN>(X, bid + 1, tid, g);

        // ---- x B-frags from LDS (2-way ds_read_b128, free) ----
        bf16x8 xb[2];
#pragma unroll
        for (int t = 0; t < 2; ++t) {
            bf16x8 v = zf;
            if (qd == 0) {
                const int row = (2 * w + t) * 16 + ln;
                v = ld_frag(&sm.xs[cur][row * 8]);
            }
            xb[t] = v;
        }

        // ---- L1: K=32 (b1 in weight pad row, x pad=1.0), C = 0 ----
        floatx4 a1[2][4];
#pragma unroll
        for (int mt = 0; mt < 4; ++mt)
#pragma unroll
            for (int t = 0; t < 2; ++t)
                a1[t][mt] = __builtin_amdgcn_mfma_f32_16x16x32_bf16(w1f[mt], xb[t], z4, 0, 0, 0);
        bf16x8 f1[2][2];
#pragma unroll
        for (int t = 0; t < 2; ++t)
#pragma unroll
            for (int kq = 0; kq < 2; ++kq)
                f1[t][kq] = pack_relu2(a1[t][2 * kq], a1[t][2 * kq + 1]);

        // ---- L2: 64 -> 64, bias from LDS as acc init ----
        floatx4 a2[2][4];
#pragma unroll
        for (int mt = 0; mt < 4; ++mt) {
            floatx4 bv = *(const floatx4*)&sm.bs[mt * 16 + qd * 4];
#pragma unroll
            for (int t = 0; t < 2; ++t) {
                floatx4 acc;
                acc = __builtin_amdgcn_mfma_f32_16x16x32_bf16(w2f[mt][0], f1[t][0], bv, 0, 0, 0);
                acc = __builtin_amdgcn_mfma_f32_16x16x32_bf16(w2f[mt][1], f1[t][1], acc, 0, 0, 0);
                a2[t][mt] = acc;
            }
        }
        bf16x8 f2[2][2];
#pragma unroll
        for (int t = 0; t < 2; ++t)
#pragma unroll
            for (int kq = 0; kq < 2; ++kq)
                f2[t][kq] = pack_relu2(a2[t][2 * kq], a2[t][2 * kq + 1]);

        // ---- L3 FLIPPED: A=f2 (rows=x-rows), B=w3 (cols=features), C=0.
        // a3[t][mt][jj] = e[xrow=(2w+t)*16+qd*4+jj][feat=mt*16+ln]
        floatx4 a3[2][2];
#pragma unroll
        for (int mt = 0; mt < 2; ++mt)
#pragma unroll
            for (int t = 0; t < 2; ++t) {
                floatx4 acc;
                acc = __builtin_amdgcn_mfma_f32_16x16x32_bf16(f2[t][0], w3f[mt][0], z4, 0, 0, 0);
                acc = __builtin_amdgcn_mfma_f32_16x16x32_bf16(f2[t][1], w3f[mt][1], acc, 0, 0, 0);
                a3[t][mt] = acc;
            }

        // ---- in-register pool over this wave's 32 x-rows ----
        float2 part[2];
#pragma unroll
        for (int mt = 0; mt < 2; ++mt) {
            floatx4 sv = a3[0][mt] + a3[1][mt];
            floatx4 mv = vmax4(a3[0][mt], a3[1][mt]);
            float s = (sv[0] + sv[1]) + (sv[2] + sv[3]);
            float m = fmaxf(fmaxf(mv[0], mv[1]), fmaxf(mv[2], mv[3]));
            s += __shfl_xor(s, 16); m = fmaxf(m, __shfl_xor(m, 16));
            s += __shfl_xor(s, 32); m = fmaxf(m, __shfl_xor(m, 32));
            part[mt] = make_float2(s, m);
        }

        if (it + 1 < ITERS) x_store<DIN>(sm.xs[cur ^ 1], tid, g);

        if (qd == 0) {
            sm.pb[pbuf * 128 + w * 32 + ln]      = part[0];
            sm.pb[pbuf * 128 + w * 32 + 16 + ln] = part[1];
        }
        __syncthreads();

        // ---- combine waves -> output (wave w holds rows [w*32,w*32+32)) ----
        if (tid < NB * 32) {
            const int b = tid >> 5, f = tid & 31;
            constexpr int WPB = 4 / NB;   // waves per batch
            float s = 0.0f, m = -3.4e38f;
#pragma unroll
            for (int wv = 0; wv < WPB; ++wv) {
                float2 v = sm.pb[pbuf * 128 + (b * WPB + wv) * 32 + f];
                s += v.x;
                m = fmaxf(m, v.y);
            }
            out[((size_t)bid * NB + b) * 32 + f] =
                (__bf16)(0.5f * (s * (1.0f / S) + m) + b3f);
        }
        cur ^= 1; pbuf ^= 1;
    }
}

__global__ __launch_bounds__(256, 4)
void enc_fused(const float* __restrict__ rX, const float* __restrict__ tX,
               const __bf16* __restrict__ wb,
               const float* __restrict__ rb2, const float* __restrict__ rb3,
               const float* __restrict__ tb2, const float* __restrict__ tb3,
               __bf16* __restrict__ remb, __bf16* __restrict__ temb)
{
    __shared__ EncSmem sm;
    if ((int)blockIdx.x < 1024)
        enc_loop<6, 64, 8>(sm, rX, wb, wb + 2048, wb + 6144,
                           rb2, rb3, remb, blockIdx.x * 8);
    else
        enc_loop<7, 128, 8>(sm, tX, wb + 8192, wb + 10240, wb + 14336,
                            tb2, tb3, temb, ((int)blockIdx.x - 1024) * 8);
}

// ---------------------------------------------------------------------------
// Head, register-chained (R7): stage c (1 barrier), then L1->L2->L3->dot in
// regs per wave (16 rows each). hw2/hw3 k-permuted; hw1/b*/w4 natural.
// ---------------------------------------------------------------------------
__global__ __launch_bounds__(256)
void head_mfma(const float* __restrict__ t0,
               const __bf16* __restrict__ remb, const __bf16* __restrict__ temb,
               const __bf16* __restrict__ hw1, const float* __restrict__ b1,
               const __bf16* __restrict__ hw2, const float* __restrict__ b2,
               const __bf16* __restrict__ hw3, const float* __restrict__ b3,
               const float* __restrict__ w4, const float* __restrict__ b4,
               float* __restrict__ out)
{
    __shared__ __align__(16) __bf16 cb[64 * 136];

    const int tid = threadIdx.x;
    const int w   = tid >> 6;
    const int l64 = tid & 63;
    const int ln  = l64 & 15;
    const int qd  = l64 >> 4;
    const int g0  = blockIdx.x * 64;

    for (int i = tid; i < 64 * 44; i += 256) {
        int r = i / 44, k = i - r * 44;
        cb[r * 136 + k] = (__bf16)t0[(size_t)(g0 + r) * 44 + k];
    }
    for (int i = tid; i < 64 * 32; i += 256) {
        int r = i >> 5, k = i & 31;
        cb[r * 136 + 44 + k] = remb[(size_t)(g0 + r) * 32 + k];
        cb[r * 136 + 76 + k] = temb[(size_t)(g0 + r) * 32 + k];
    }
    for (int i = tid; i < 64 * 20; i += 256) {
        int r = i / 20, k = i - r * 20;
        cb[r * 136 + 108 + k] = (__bf16)0.0f;
    }
    __syncthreads();

    bf16x8 cf[4];
#pragma unroll
    for (int kq = 0; kq < 4; ++kq)
        cf[kq] = ld_frag(&cb[(w * 16 + ln) * 136 + kq * 32 + qd * 8]);
    floatx4 acc1[8];
#pragma unroll
    for (int mt = 0; mt < 8; ++mt) {
        float4 bv = *(const float4*)&b1[mt * 16 + qd * 4];
        floatx4 acc = (floatx4){bv.x, bv.y, bv.z, bv.w};
#pragma unroll
        for (int kq = 0; kq < 4; ++kq) {
            bf16x8 af = ld_frag(&hw1[(mt * 16 + ln) * 128 + kq * 32 + qd * 8]);
            acc = __builtin_amdgcn_mfma_f32_16x16x32_bf16(af, cf[kq], acc, 0, 0, 0);
        }
        acc1[mt] = acc;
    }
    bf16x8 f1[4];
#pragma unroll
    for (int kq = 0; kq < 4; ++kq)
        f1[kq] = pack_relu2(acc1[2 * kq], acc1[2 * kq + 1]);

    floatx4 acc2[8];
#pragma unroll
    for (int mt = 0; mt < 8; ++mt) {
        float4 bv = *(const float4*)&b2[mt * 16 + qd * 4];
        floatx4 acc = (floatx4){bv.x, bv.y, bv.z, bv.w};
#pragma unroll
        for (int kq = 0; kq < 4; ++kq) {
            bf16x8 af = ld_frag(&hw2[(mt * 16 + ln) * 128 + kq * 32 + qd * 8]);
            acc = __builtin_amdgcn_mfma_f32_16x16x32_bf16(af, f1[kq], acc, 0, 0, 0);
        }
        acc2[mt] = acc;
    }
    bf16x8 f2[4];
#pragma unroll
    for (int kq = 0; kq < 4; ++kq)
        f2[kq] = pack_relu2(acc2[2 * kq], acc2[2 * kq + 1]);

    floatx4 acc3[4];
#pragma unroll
    for (int mt = 0; mt < 4; ++mt) {
        float4 bv = *(const float4*)&b3[mt * 16 + qd * 4];
        floatx4 acc = (floatx4){bv.x, bv.y, bv.z, bv.w};
#pragma unroll
        for (int kq = 0; kq < 4; ++kq) {
            bf16x8 af = ld_frag(&hw3[(mt * 16 + ln) * 128 + kq * 32 + qd * 8]);
            acc = __builtin_amdgcn_mfma_f32_16x16x32_bf16(af, f2[kq], acc, 0, 0, 0);
        }
        acc3[mt] = acc;
    }

    float part = 0.0f;
#pragma unroll
    for (int mt = 0; mt < 4; ++mt) {
        float4 wv = *(const float4*)&w4[mt * 16 + qd * 4];
        part = fmaf(fmaxf(acc3[mt][0], 0.0f), wv.x, part);
        part = fmaf(fmaxf(acc3[mt][1], 0.0f), wv.y, part);
        part = fmaf(fmaxf(acc3[mt][2], 0.0f), wv.z, part);
        part = fmaf(fmaxf(acc3[mt][3], 0.0f), wv.w, part);
    }
    part += __shfl_xor(part, 16);
    part += __shfl_xor(part, 32);
    if (qd == 0)
        out[g0 + w * 16 + ln] = part + b4[0];
}

extern "C" void kernel_launch(void* const* d_in, const int* in_sizes, int n_in,
                              void* d_out, int out_size, void* d_ws, size_t ws_size,
                              hipStream_t stream)
{
    const float* t0  = (const float*)d_in[0];
    const float* rX  = (const float*)d_in[1];
    const float* tX  = (const float*)d_in[2];
    const float* rw1 = (const float*)d_in[3];  const float* rb1 = (const float*)d_in[4];
    const float* rw2 = (const float*)d_in[5];  const float* rb2 = (const float*)d_in[6];
    const float* rw3 = (const float*)d_in[7];  const float* rb3 = (const float*)d_in[8];
    const float* tw1 = (const float*)d_in[9];  const float* tb1 = (const float*)d_in[10];
    const float* tw2 = (const float*)d_in[11]; const float* tb2 = (const float*)d_in[12];
    const float* tw3 = (const float*)d_in[13]; const float* tb3 = (const float*)d_in[14];
    const float* mw1 = (const float*)d_in[15]; const float* mb1 = (const float*)d_in[16];
    const float* mw2 = (const float*)d_in[17]; const float* mb2 = (const float*)d_in[18];
    const float* mw3 = (const float*)d_in[19]; const float* mb3 = (const float*)d_in[20];
    const float* mw4 = (const float*)d_in[21]; const float* mb4 = (const float*)d_in[22];
    float* out = (float*)d_out;

    const int B = 16384;
    __bf16* remb = (__bf16*)d_ws;
    __bf16* temb = (__bf16*)((char*)d_ws + ((size_t)1 << 20));
    __bf16* wb   = (__bf16*)((char*)d_ws + ((size_t)2 << 20));
    const __bf16* mw1b = wb + 16384; const __bf16* mw2b = wb + 32768;
    const __bf16* mw3b = wb + 49152;

    prep_kernel<<<64, 256, 0, stream>>>(rw1, rb1, rw2, rw3, tw1, tb1, tw2, tw3,
                                        mw1, mw2, mw3, wb);
    enc_fused<<<3072, 256, 0, stream>>>(rX, tX, wb,
                                        rb2, rb3, tb2, tb3,
                                        remb, temb);
    head_mfma<<<B / 64, 256, 0, stream>>>(t0, remb, temb,
                                          mw1b, mb1, mw2b, mb2, mw3b, mb3,
                                          mw4, mb4, out);
}

// Round 4
// 211.577 us; speedup vs baseline: 2.1531x; 1.0695x over previous
//
#include <hip/hip_runtime.h>
#include <hip/hip_bf16.h>

#define DEV_INLINE __device__ __forceinline__

typedef __bf16 bf16x8 __attribute__((ext_vector_type(8)));
typedef float  floatx4 __attribute__((ext_vector_type(4)));

DEV_INLINE bf16x8 ld_frag(const __bf16* p) {
    union { uint4 u; bf16x8 v; } t;
    t.u = *(const uint4*)p;
    return t.v;
}
// relu + pack two f32x4 accumulators into the next layer's B-fragment.
// Element j of the frag = relu(acc[2kq + (j>>2)][j&3]) -> matches tp_perm:
// feat(k_hw) = (2*kq + (j>>2))*16 + qd*4 + (j&3).
DEV_INLINE bf16x8 pack_relu2(floatx4 a, floatx4 b) {
    float2 p0 = {fmaxf(a[0], 0.0f), fmaxf(a[1], 0.0f)};
    float2 p1 = {fmaxf(a[2], 0.0f), fmaxf(a[3], 0.0f)};
    float2 p2 = {fmaxf(b[0], 0.0f), fmaxf(b[1], 0.0f)};
    float2 p3 = {fmaxf(b[2], 0.0f), fmaxf(b[3], 0.0f)};
    union { __hip_bfloat162 h[4]; bf16x8 v; } t;
    t.h[0] = __float22bfloat162_rn(p0);
    t.h[1] = __float22bfloat162_rn(p1);
    t.h[2] = __float22bfloat162_rn(p2);
    t.h[3] = __float22bfloat162_rn(p3);
    return t.v;
}
DEV_INLINE floatx4 vmax4(floatx4 a, floatx4 b) {
    floatx4 r;
#pragma unroll
    for (int i = 0; i < 4; ++i) r[i] = fmaxf(a[i], b[i]);
    return r;
}

// ---------------------------------------------------------------------------
// Prep. tp: natural transpose+pad (A-layout [n][k]). tp_b: same, with the
// bias placed in padded row k==Ks (consumer sets x[k=Ks]=1.0). tp_perm:
// k-permuted so the consumer uses the previous layer's accumulators directly.
// ---------------------------------------------------------------------------
template<int N, int Kp, int Ks>
DEV_INLINE void tp(__bf16* dst, const float* __restrict__ src, int idx0, int stride) {
    for (int e = idx0; e < N * Kp; e += stride) {
        int n = e / Kp, k = e - n * Kp;
        dst[e] = (k < Ks) ? (__bf16)src[k * N + n] : (__bf16)0.0f;
    }
}
template<int N, int Kp, int Ks>
DEV_INLINE void tp_b(__bf16* dst, const float* __restrict__ src,
                     const float* __restrict__ bias, int idx0, int stride) {
    for (int e = idx0; e < N * Kp; e += stride) {
        int n = e / Kp, k = e - n * Kp;
        float v = (k < Ks) ? src[k * N + n] : ((k == Ks) ? bias[n] : 0.0f);
        dst[e] = (__bf16)v;
    }
}
template<int N, int K>   // dst[n][k_hw] = src[c(k_hw)][n]
DEV_INLINE void tp_perm(__bf16* dst, const float* __restrict__ src, int idx0, int stride) {
    for (int e = idx0; e < N * K; e += stride) {
        int n = e / K, kh = e - n * K;
        int qd = (kh >> 3) & 3, kq = kh >> 5, j = kh & 7;
        int c = (2 * kq + (j >> 2)) * 16 + qd * 4 + (j & 3);
        dst[e] = (__bf16)src[c * N + n];
    }
}

__global__ __launch_bounds__(256)
void prep_kernel(const float* __restrict__ rw1, const float* __restrict__ rb1,
                 const float* __restrict__ rw2, const float* __restrict__ rw3,
                 const float* __restrict__ tw1, const float* __restrict__ tb1,
                 const float* __restrict__ tw2, const float* __restrict__ tw3,
                 const float* __restrict__ mw1, const float* __restrict__ mw2,
                 const float* __restrict__ mw3, __bf16* __restrict__ wb)
{
    int i0 = blockIdx.x * 256 + threadIdx.x;
    int st = gridDim.x * 256;
    tp_b   < 64,  32,   6>(wb + 0,     rw1, rb1, i0, st);
    tp_perm< 64,  64>     (wb + 2048,  rw2, i0, st);
    tp_perm< 32,  64>     (wb + 6144,  rw3, i0, st);
    tp_b   < 64,  32,   7>(wb + 8192,  tw1, tb1, i0, st);
    tp_perm< 64,  64>     (wb + 10240, tw2, i0, st);
    tp_perm< 32,  64>     (wb + 14336, tw3, i0, st);
    tp     <128, 128, 108>(wb + 16384, mw1, i0, st);
    tp_perm<128, 128>     (wb + 32768, mw2, i0, st);
    tp_perm< 64, 128>     (wb + 49152, mw3, i0, st);
}

// ---------------------------------------------------------------------------
// Persistent fused encoder, R11: weights live in LDS (shared by the block's
// 4 waves) and are streamed as short-lived frags per MFMA. Per-thread unified
// registers drop ~128 -> ~80 => __launch_bounds__(256,6) for 6 blocks/CU.
// w2/w3 frag reads hit a 64B half of each 128B row -> XOR-swizzle byte bits
// 4..6 with row&7 (applied once at copy + folded into per-thread base).
// w1 frag reads cover whole 64B rows (uniform banks, no swizzle).
// ---------------------------------------------------------------------------
struct __align__(16) EncSmem {
    __bf16 wt[8192];         // w1(0..4095B) | w2(4096..) | w3(12288..)  16 KB
    float2 pb[2 * 128];      // wave partials (sum,max), dbuf  2048 B
    float  bs[64];           // b2                              256 B
    __bf16 xs[2][128 * 8];   // x tiles, k padded to 8         4096 B
};

template<int DIN>
DEV_INLINE void x_load(const float* __restrict__ X, int bid, int tid, float (&g)[4]) {
    const float* src = X + (size_t)bid * 128 * DIN;
#pragma unroll
    for (int p = 0; p < 4; ++p) {
        int e = tid + p * 256;
        if ((DIN == 6) ? (p < 3) : (e < 128 * 7)) g[p] = src[e];
    }
}
template<int DIN>
DEV_INLINE void x_store(__bf16* xbuf, int tid, const float (&g)[4]) {
#pragma unroll
    for (int p = 0; p < 4; ++p) {
        int e = tid + p * 256;
        if ((DIN == 6) ? (p < 3) : (e < 128 * 7)) {
            int r = e / DIN, k = e - r * DIN;
            xbuf[r * 8 + k] = (__bf16)g[p];
        }
    }
}

template<int DIN, int S, int ITERS>
DEV_INLINE void enc_loop(EncSmem& sm, const float* __restrict__ X,
                         const __bf16* __restrict__ wsrc,
                         const float* __restrict__ b2, const float* __restrict__ b3,
                         __bf16* __restrict__ out, int bid0)
{
    constexpr int NB = 128 / S;          // batches per 128-row tile
    const int tid = threadIdx.x;
    const int w   = tid >> 6;
    const int l64 = tid & 63;
    const int ln  = l64 & 15;
    const int qd  = l64 >> 4;

    if (tid < 64) sm.bs[tid] = b2[tid];

    // ---- weights -> LDS once per block (swizzled copy, 4 chunks/thread) ----
    for (int c = tid; c < 1024; c += 256) {
        uint4 v = *(const uint4*)(wsrc + c * 8);
        int byte = c * 16;
        int dst  = (c < 256) ? byte                                   // w1: no swizzle
                             : (byte ^ (((byte >> 7) & 7) << 4));     // w2/w3: row&7 xor
        *(uint4*)((char*)sm.wt + dst) = v;
    }

    // pad init: k in [DIN,8) of both x buffers; bias slot k==DIN gets 1.0
    {
        __bf16* xf = &sm.xs[0][0];
        if (DIN == 6) {
            union { __bf16 h[2]; uint32_t u; } c;
            c.h[0] = (__bf16)1.0f; c.h[1] = (__bf16)0.0f;
            *(uint32_t*)&xf[tid * 8 + 6] = c.u;   // rows 0..255 across both bufs
        } else {
            xf[tid * 8 + 7] = (__bf16)1.0f;
        }
    }
    // b3 folded past pooling: e-row = Wx + b3 -> 0.5*(mean+max) = 0.5*(s/S+m)+b3[f]
    const float b3f = (tid < NB * 32) ? b3[tid & 31] : 0.0f;

    // per-thread weight base byte offsets (swizzle folded in; mt/kq offsets
    // are compile-time immediates that don't touch the swizzled bits)
    const int wb1   = (ln * 32 + qd * 8) * 2;                               // w1, stride 64B
    const int wb64a = ((ln * 64 + qd * 8) * 2)       ^ ((ln & 7) << 4);     // w2/w3 kq=0
    const int wb64b = ((ln * 64 + 32 + qd * 8) * 2)  ^ ((ln & 7) << 4);     // w2/w3 kq=1
    const char* wtb = (const char*)sm.wt;

    bf16x8 zf;
#pragma unroll
    for (int j = 0; j < 8; ++j) zf[j] = (__bf16)0.0f;
    const floatx4 z4 = {0.0f, 0.0f, 0.0f, 0.0f};

    // ---- prologue: stage x for iter 0 ----
    float g[4];
    x_load<DIN>(X, bid0, tid, g);
    x_store<DIN>(sm.xs[0], tid, g);
    __syncthreads();

    int cur = 0, pbuf = 0;
    for (int it = 0; it < ITERS; ++it) {
        const int bid = bid0 + it;
        // issue next tile's global loads early; stored late (latency hidden
        // under the whole L1->L3 compute). Writing xs[cur^1] needs no barrier:
        // its last reads were ordered by the previous iter's barrier.
        if (it + 1 < ITERS) x_load<DIN>(X, bid + 1, tid, g);

        // ---- x B-frags from LDS (2-way ds_read_b128, free) ----
        bf16x8 xb[2];
#pragma unroll
        for (int t = 0; t < 2; ++t) {
            bf16x8 v = zf;
            if (qd == 0) {
                const int row = (2 * w + t) * 16 + ln;
                v = ld_frag(&sm.xs[cur][row * 8]);
            }
            xb[t] = v;
        }

        // ---- L1: K=32 (b1 in weight pad row, x pad=1.0), C = 0 ----
        floatx4 a1[2][4];
#pragma unroll
        for (int mt = 0; mt < 4; ++mt) {
            bf16x8 wf = ld_frag((const __bf16*)(wtb + wb1 + mt * 1024));
#pragma unroll
            for (int t = 0; t < 2; ++t)
                a1[t][mt] = __builtin_amdgcn_mfma_f32_16x16x32_bf16(wf, xb[t], z4, 0, 0, 0);
        }
        bf16x8 f1[2][2];
#pragma unroll
        for (int t = 0; t < 2; ++t)
#pragma unroll
            for (int kq = 0; kq < 2; ++kq)
                f1[t][kq] = pack_relu2(a1[t][2 * kq], a1[t][2 * kq + 1]);

        // ---- L2: 64 -> 64, rolling a2 -> f2 per mt-pair (reg cap) ----
        bf16x8 f2[2][2];
#pragma unroll
        for (int pr = 0; pr < 2; ++pr) {
            floatx4 a2[2][2];
#pragma unroll
            for (int m = 0; m < 2; ++m) {
                const int mt = pr * 2 + m;
                floatx4 bv = *(const floatx4*)&sm.bs[mt * 16 + qd * 4];
                bf16x8 wf0 = ld_frag((const __bf16*)(wtb + 4096 + mt * 2048 + wb64a));
                bf16x8 wf1 = ld_frag((const __bf16*)(wtb + 4096 + mt * 2048 + wb64b));
#pragma unroll
                for (int t = 0; t < 2; ++t) {
                    floatx4 acc;
                    acc = __builtin_amdgcn_mfma_f32_16x16x32_bf16(wf0, f1[t][0], bv, 0, 0, 0);
                    acc = __builtin_amdgcn_mfma_f32_16x16x32_bf16(wf1, f1[t][1], acc, 0, 0, 0);
                    a2[t][m] = acc;
                }
            }
#pragma unroll
            for (int t = 0; t < 2; ++t)
                f2[t][pr] = pack_relu2(a2[t][0], a2[t][1]);
        }

        // ---- L3 FLIPPED: A=f2 (rows=x-rows), B=w3 (cols=features), C=0.
        // a3[t][mt][jj] = e[xrow=(2w+t)*16+qd*4+jj][feat=mt*16+ln]
        floatx4 a3[2][2];
#pragma unroll
        for (int mt = 0; mt < 2; ++mt) {
            bf16x8 wf0 = ld_frag((const __bf16*)(wtb + 12288 + mt * 2048 + wb64a));
            bf16x8 wf1 = ld_frag((const __bf16*)(wtb + 12288 + mt * 2048 + wb64b));
#pragma unroll
            for (int t = 0; t < 2; ++t) {
                floatx4 acc;
                acc = __builtin_amdgcn_mfma_f32_16x16x32_bf16(f2[t][0], wf0, z4, 0, 0, 0);
                acc = __builtin_amdgcn_mfma_f32_16x16x32_bf16(f2[t][1], wf1, acc, 0, 0, 0);
                a3[t][mt] = acc;
            }
        }

        // ---- in-register pool over this wave's 32 x-rows ----
        float2 part[2];
#pragma unroll
        for (int mt = 0; mt < 2; ++mt) {
            floatx4 sv = a3[0][mt] + a3[1][mt];
            floatx4 mv = vmax4(a3[0][mt], a3[1][mt]);
            float s = (sv[0] + sv[1]) + (sv[2] + sv[3]);
            float m = fmaxf(fmaxf(mv[0], mv[1]), fmaxf(mv[2], mv[3]));
            s += __shfl_xor(s, 16); m = fmaxf(m, __shfl_xor(m, 16));
            s += __shfl_xor(s, 32); m = fmaxf(m, __shfl_xor(m, 32));
            part[mt] = make_float2(s, m);
        }

        if (it + 1 < ITERS) x_store<DIN>(sm.xs[cur ^ 1], tid, g);

        if (qd == 0) {
            sm.pb[pbuf * 128 + w * 32 + ln]      = part[0];
            sm.pb[pbuf * 128 + w * 32 + 16 + ln] = part[1];
        }
        __syncthreads();

        // ---- combine waves -> output (wave w holds rows [w*32,w*32+32)) ----
        if (tid < NB * 32) {
            const int b = tid >> 5, f = tid & 31;
            constexpr int WPB = 4 / NB;   // waves per batch
            float s = 0.0f, m = -3.4e38f;
#pragma unroll
            for (int wv = 0; wv < WPB; ++wv) {
                float2 v = sm.pb[pbuf * 128 + (b * WPB + wv) * 32 + f];
                s += v.x;
                m = fmaxf(m, v.y);
            }
            out[((size_t)bid * NB + b) * 32 + f] =
                (__bf16)(0.5f * (s * (1.0f / S) + m) + b3f);
        }
        cur ^= 1; pbuf ^= 1;
    }
}

__global__ __launch_bounds__(256, 6)
void enc_fused(const float* __restrict__ rX, const float* __restrict__ tX,
               const __bf16* __restrict__ wb,
               const float* __restrict__ rb2, const float* __restrict__ rb3,
               const float* __restrict__ tb2, const float* __restrict__ tb3,
               __bf16* __restrict__ remb, __bf16* __restrict__ temb)
{
    __shared__ EncSmem sm;
    if ((int)blockIdx.x < 1024)
        enc_loop<6, 64, 8>(sm, rX, wb, rb2, rb3, remb, blockIdx.x * 8);
    else
        enc_loop<7, 128, 8>(sm, tX, wb + 8192, tb2, tb3, temb,
                            ((int)blockIdx.x - 1024) * 8);
}

// ---------------------------------------------------------------------------
// Head, register-chained (R7): stage c (1 barrier), then L1->L2->L3->dot in
// regs per wave (16 rows each). hw2/hw3 k-permuted; hw1/b*/w4 natural.
// ---------------------------------------------------------------------------
__global__ __launch_bounds__(256)
void head_mfma(const float* __restrict__ t0,
               const __bf16* __restrict__ remb, const __bf16* __restrict__ temb,
               const __bf16* __restrict__ hw1, const float* __restrict__ b1,
               const __bf16* __restrict__ hw2, const float* __restrict__ b2,
               const __bf16* __restrict__ hw3, const float* __restrict__ b3,
               const float* __restrict__ w4, const float* __restrict__ b4,
               float* __restrict__ out)
{
    __shared__ __align__(16) __bf16 cb[64 * 136];

    const int tid = threadIdx.x;
    const int w   = tid >> 6;
    const int l64 = tid & 63;
    const int ln  = l64 & 15;
    const int qd  = l64 >> 4;
    const int g0  = blockIdx.x * 64;

    for (int i = tid; i < 64 * 44; i += 256) {
        int r = i / 44, k = i - r * 44;
        cb[r * 136 + k] = (__bf16)t0[(size_t)(g0 + r) * 44 + k];
    }
    for (int i = tid; i < 64 * 32; i += 256) {
        int r = i >> 5, k = i & 31;
        cb[r * 136 + 44 + k] = remb[(size_t)(g0 + r) * 32 + k];
        cb[r * 136 + 76 + k] = temb[(size_t)(g0 + r) * 32 + k];
    }
    for (int i = tid; i < 64 * 20; i += 256) {
        int r = i / 20, k = i - r * 20;
        cb[r * 136 + 108 + k] = (__bf16)0.0f;
    }
    __syncthreads();

    bf16x8 cf[4];
#pragma unroll
    for (int kq = 0; kq < 4; ++kq)
        cf[kq] = ld_frag(&cb[(w * 16 + ln) * 136 + kq * 32 + qd * 8]);
    floatx4 acc1[8];
#pragma unroll
    for (int mt = 0; mt < 8; ++mt) {
        float4 bv = *(const float4*)&b1[mt * 16 + qd * 4];
        floatx4 acc = (floatx4){bv.x, bv.y, bv.z, bv.w};
#pragma unroll
        for (int kq = 0; kq < 4; ++kq) {
            bf16x8 af = ld_frag(&hw1[(mt * 16 + ln) * 128 + kq * 32 + qd * 8]);
            acc = __builtin_amdgcn_mfma_f32_16x16x32_bf16(af, cf[kq], acc, 0, 0, 0);
        }
        acc1[mt] = acc;
    }
    bf16x8 f1[4];
#pragma unroll
    for (int kq = 0; kq < 4; ++kq)
        f1[kq] = pack_relu2(acc1[2 * kq], acc1[2 * kq + 1]);

    floatx4 acc2[8];
#pragma unroll
    for (int mt = 0; mt < 8; ++mt) {
        float4 bv = *(const float4*)&b2[mt * 16 + qd * 4];
        floatx4 acc = (floatx4){bv.x, bv.y, bv.z, bv.w};
#pragma unroll
        for (int kq = 0; kq < 4; ++kq) {
            bf16x8 af = ld_frag(&hw2[(mt * 16 + ln) * 128 + kq * 32 + qd * 8]);
            acc = __builtin_amdgcn_mfma_f32_16x16x32_bf16(af, f1[kq], acc, 0, 0, 0);
        }
        acc2[mt] = acc;
    }
    bf16x8 f2[4];
#pragma unroll
    for (int kq = 0; kq < 4; ++kq)
        f2[kq] = pack_relu2(acc2[2 * kq], acc2[2 * kq + 1]);

    floatx4 acc3[4];
#pragma unroll
    for (int mt = 0; mt < 4; ++mt) {
        float4 bv = *(const float4*)&b3[mt * 16 + qd * 4];
        floatx4 acc = (floatx4){bv.x, bv.y, bv.z, bv.w};
#pragma unroll
        for (int kq = 0; kq < 4; ++kq) {
            bf16x8 af = ld_frag(&hw3[(mt * 16 + ln) * 128 + kq * 32 + qd * 8]);
            acc = __builtin_amdgcn_mfma_f32_16x16x32_bf16(af, f2[kq], acc, 0, 0, 0);
        }
        acc3[mt] = acc;
    }

    float part = 0.0f;
#pragma unroll
    for (int mt = 0; mt < 4; ++mt) {
        float4 wv = *(const float4*)&w4[mt * 16 + qd * 4];
        part = fmaf(fmaxf(acc3[mt][0], 0.0f), wv.x, part);
        part = fmaf(fmaxf(acc3[mt][1], 0.0f), wv.y, part);
        part = fmaf(fmaxf(acc3[mt][2], 0.0f), wv.z, part);
        part = fmaf(fmaxf(acc3[mt][3], 0.0f), wv.w, part);
    }
    part += __shfl_xor(part, 16);
    part += __shfl_xor(part, 32);
    if (qd == 0)
        out[g0 + w * 16 + ln] = part + b4[0];
}

extern "C" void kernel_launch(void* const* d_in, const int* in_sizes, int n_in,
                              void* d_out, int out_size, void* d_ws, size_t ws_size,
                              hipStream_t stream)
{
    const float* t0  = (const float*)d_in[0];
    const float* rX  = (const float*)d_in[1];
    const float* tX  = (const float*)d_in[2];
    const float* rw1 = (const float*)d_in[3];  const float* rb1 = (const float*)d_in[4];
    const float* rw2 = (const float*)d_in[5];  const float* rb2 = (const float*)d_in[6];
    const float* rw3 = (const float*)d_in[7];  const float* rb3 = (const float*)d_in[8];
    const float* tw1 = (const float*)d_in[9];  const float* tb1 = (const float*)d_in[10];
    const float* tw2 = (const float*)d_in[11]; const float* tb2 = (const float*)d_in[12];
    const float* tw3 = (const float*)d_in[13]; const float* tb3 = (const float*)d_in[14];
    const float* mw1 = (const float*)d_in[15]; const float* mb1 = (const float*)d_in[16];
    const float* mw2 = (const float*)d_in[17]; const float* mb2 = (const float*)d_in[18];
    const float* mw3 = (const float*)d_in[19]; const float* mb3 = (const float*)d_in[20];
    const float* mw4 = (const float*)d_in[21]; const float* mb4 = (const float*)d_in[22];
    float* out = (float*)d_out;

    const int B = 16384;
    __bf16* remb = (__bf16*)d_ws;
    __bf16* temb = (__bf16*)((char*)d_ws + ((size_t)1 << 20));
    __bf16* wb   = (__bf16*)((char*)d_ws + ((size_t)2 << 20));
    const __bf16* mw1b = wb + 16384; const __bf16* mw2b = wb + 32768;
    const __bf16* mw3b = wb + 49152;

    prep_kernel<<<64, 256, 0, stream>>>(rw1, rb1, rw2, rw3, tw1, tb1, tw2, tw3,
                                        mw1, mw2, mw3, wb);
    enc_fused<<<3072, 256, 0, stream>>>(rX, tX, wb,
                                        rb2, rb3, tb2, tb3,
                                        remb, temb);
    head_mfma<<<B / 64, 256, 0, stream>>>(t0, remb, temb,
                                          mw1b, mb1, mw2b, mb2, mw3b, mb3,
                                          mw4, mb4, out);
}